// Round 14
// baseline (66.757 us; speedup 1.0000x reference)
//
#include <hip/hip_runtime.h>

#define DM 2048
#define DS 16
#define SEQ 4096
#define P 4096      // batch * d_model independent scans
#define NP (P / 2)  // thread handles 2 adjacent channels
#define NC 32       // chunks
#define LST 128     // SEQ / NC
#define UNR 16

// Rescaled state: g' = Abar*g + x  (Abar = exp(-delta*exp(A_log)));
// y = sum_n CB[n]*g[n] + D*x, CB = C*delta*B.  Params computed inline.
// 3 plain kernels (no cross-block sync / no coop launch / no NT hints —
// all measured slower on gfx950). Each thread owns TWO adjacent channels so
// every x load / y store is a float2 (512 B per wave-instr vs 256 B scalar).
// ws: agg [NC][P][16 bf16] (4 MB) — thread's 2 channels contiguous (64 B).

__device__ __forceinline__ unsigned short f2bf(float f) {
  unsigned int u = __builtin_bit_cast(unsigned int, f);
  u += 0x7fffu + ((u >> 16) & 1u);   // round-to-nearest-even
  return (unsigned short)(u >> 16);
}
__device__ __forceinline__ float bf2f(unsigned short s) {
  unsigned int u = ((unsigned int)s) << 16;
  return __builtin_bit_cast(float, u);
}

// ab for channels d, d+1 -> ab2[2][16]
__device__ __forceinline__ void load_ab2(const float* __restrict__ A_log, int d,
                                         float dl0, float dl1, float ab2[2][DS]) {
  const float4* alp = (const float4*)(A_log + d * DS);
#pragma unroll
  for (int c = 0; c < 2; c++) {
    float dl = c ? dl1 : dl0;
#pragma unroll
    for (int q = 0; q < 4; q++) {
      float4 v = alp[4 * c + q];
      ab2[c][4 * q + 0] = __expf(-dl * __expf(v.x));
      ab2[c][4 * q + 1] = __expf(-dl * __expf(v.y));
      ab2[c][4 * q + 2] = __expf(-dl * __expf(v.z));
      ab2[c][4 * q + 3] = __expf(-dl * __expf(v.w));
    }
  }
}

// Kernel 1: per-chunk local scan from g=0; store chunk-end aggregate (bf16).
__global__ __launch_bounds__(256, 2) void k_local(const float* __restrict__ x,
                                                  const float* __restrict__ A_log,
                                                  const float* __restrict__ delta,
                                                  unsigned int* __restrict__ agg) {
  int tid = blockIdx.x * 256 + threadIdx.x;   // NC * NP threads
  int p2 = tid & (NP - 1);
  int k = tid >> 11;            // NP = 2048
  int b = p2 >> 10;             // DM/2 = 1024 pairs per batch
  int d = (p2 & 1023) << 1;
  const float2* dlp = (const float2*)(delta + d);
  float2 dl = *dlp;
  float ab2[2][DS], g2[2][DS];
  load_ab2(A_log, d, dl.x, dl.y, ab2);
#pragma unroll
  for (int c = 0; c < 2; c++)
#pragma unroll
    for (int n = 0; n < DS; n++) g2[c][n] = 0.f;

  const float2* xp = (const float2*)(x + ((size_t)b * SEQ + (size_t)k * LST) * DM + d);
  const size_t str2 = DM / 2;   // float2 stride per time step
#pragma unroll 1
  for (int t = 0; t < LST; t += UNR) {
    float2 xv[UNR];
#pragma unroll
    for (int j = 0; j < UNR; j++) xv[j] = xp[(size_t)j * str2];
#pragma unroll
    for (int j = 0; j < UNR; j++) {
#pragma unroll
      for (int n = 0; n < DS; n++) g2[0][n] = fmaf(ab2[0][n], g2[0][n], xv[j].x);
#pragma unroll
      for (int n = 0; n < DS; n++) g2[1][n] = fmaf(ab2[1][n], g2[1][n], xv[j].y);
    }
    xp += (size_t)UNR * str2;
  }
  if (k < NC - 1) {  // last chunk's aggregate is never consumed
    unsigned int u[16];
#pragma unroll
    for (int c = 0; c < 2; c++)
#pragma unroll
      for (int q = 0; q < 8; q++)
        u[8 * c + q] = (unsigned int)f2bf(g2[c][2 * q]) |
                       ((unsigned int)f2bf(g2[c][2 * q + 1]) << 16);
    uint4* Ap = (uint4*)(agg + ((size_t)k * P + (size_t)b * DM + d) * 8);
    Ap[0] = make_uint4(u[0], u[1], u[2], u[3]);
    Ap[1] = make_uint4(u[4], u[5], u[6], u[7]);
    Ap[2] = make_uint4(u[8], u[9], u[10], u[11]);
    Ap[3] = make_uint4(u[12], u[13], u[14], u[15]);
  }
}

// Kernel 2: exclusive prefix scan over chunks; thread per (channel, n-pair).
__global__ __launch_bounds__(256) void k_scan(unsigned int* __restrict__ agg,
                                              const float* __restrict__ A_log,
                                              const float* __restrict__ delta) {
  int tid = blockIdx.x * 256 + threadIdx.x;  // P*8 threads
  int np = tid & 7;          // n-pair (n = 2*np, 2*np+1)
  int p = tid >> 3;
  int d = p & (DM - 1);
  float dl = delta[d];
  float pw0 = __expf(-dl * __expf(A_log[d * DS + 2 * np + 0]) * (float)LST);
  float pw1 = __expf(-dl * __expf(A_log[d * DS + 2 * np + 1]) * (float)LST);
  float c0 = 0.f, c1 = 0.f;
  unsigned int* Hp = agg + tid;
  const size_t stride = (size_t)P * 8;
  unsigned int v[NC];
#pragma unroll
  for (int j = 0; j < NC; j++) v[j] = Hp[(size_t)j * stride];
#pragma unroll
  for (int j = 0; j < NC; j++) {
    Hp[(size_t)j * stride] =
        (unsigned int)f2bf(c0) | ((unsigned int)f2bf(c1) << 16);
    c0 = fmaf(pw0, c0, bf2f((unsigned short)(v[j] & 0xffffu)));
    c1 = fmaf(pw1, c1, bf2f((unsigned short)(v[j] >> 16)));
  }
}

// Kernel 3: rescan each chunk from its true start state; emit y (float2).
__global__ __launch_bounds__(256, 2) void k_final(const float* __restrict__ x,
                                                  const float* __restrict__ A_log,
                                                  const float* __restrict__ B,
                                                  const float* __restrict__ C,
                                                  const float* __restrict__ Dp,
                                                  const float* __restrict__ delta,
                                                  const unsigned int* __restrict__ agg,
                                                  float* __restrict__ out) {
  int tid = blockIdx.x * 256 + threadIdx.x;   // NC * NP threads
  int p2 = tid & (NP - 1);
  int k = tid >> 11;
  int b = p2 >> 10;
  int d = (p2 & 1023) << 1;
  const float2* dlp = (const float2*)(delta + d);
  float2 dl = *dlp;
  float ab2[2][DS], cb2[2][DS], g2[2][DS];
  load_ab2(A_log, d, dl.x, dl.y, ab2);
  {
    const float4* bp = (const float4*)(B + d * DS);
    const float4* cp = (const float4*)(C + d * DS);
#pragma unroll
    for (int c = 0; c < 2; c++) {
      float dlc = c ? dl.y : dl.x;
#pragma unroll
      for (int q = 0; q < 4; q++) {
        float4 bv = bp[4 * c + q];
        float4 cv = cp[4 * c + q];
        cb2[c][4 * q + 0] = cv.x * dlc * bv.x;
        cb2[c][4 * q + 1] = cv.y * dlc * bv.y;
        cb2[c][4 * q + 2] = cv.z * dlc * bv.z;
        cb2[c][4 * q + 3] = cv.w * dlc * bv.w;
      }
    }
  }
  {
    const uint4* Ap = (const uint4*)(agg + ((size_t)k * P + (size_t)b * DM + d) * 8);
#pragma unroll
    for (int c = 0; c < 2; c++) {
      uint4 u0 = Ap[2 * c], u1 = Ap[2 * c + 1];
      unsigned int u[8] = {u0.x, u0.y, u0.z, u0.w, u1.x, u1.y, u1.z, u1.w};
#pragma unroll
      for (int q = 0; q < 8; q++) {
        g2[c][2 * q + 0] = bf2f((unsigned short)(u[q] & 0xffffu));
        g2[c][2 * q + 1] = bf2f((unsigned short)(u[q] >> 16));
      }
    }
  }
  const float2* ddp = (const float2*)(Dp + d);
  float2 Dd = *ddp;
  size_t off = ((size_t)b * SEQ + (size_t)k * LST) * DM + d;
  const float2* xp = (const float2*)(x + off);
  float2* yp = (float2*)(out + off);
  const size_t str2 = DM / 2;
#pragma unroll 1
  for (int t = 0; t < LST; t += UNR) {
    float2 xv[UNR];
#pragma unroll
    for (int j = 0; j < UNR; j++) xv[j] = xp[(size_t)j * str2];
#pragma unroll
    for (int j = 0; j < UNR; j++) {
#pragma unroll
      for (int n = 0; n < DS; n++) g2[0][n] = fmaf(ab2[0][n], g2[0][n], xv[j].x);
#pragma unroll
      for (int n = 0; n < DS; n++) g2[1][n] = fmaf(ab2[1][n], g2[1][n], xv[j].y);
      float a0 = Dd.x * xv[j].x;
      float a1 = Dd.y * xv[j].y;
#pragma unroll
      for (int n = 0; n < DS; n++) a0 = fmaf(cb2[0][n], g2[0][n], a0);
#pragma unroll
      for (int n = 0; n < DS; n++) a1 = fmaf(cb2[1][n], g2[1][n], a1);
      yp[(size_t)j * str2] = make_float2(a0, a1);
    }
    xp += (size_t)UNR * str2;
    yp += (size_t)UNR * str2;
  }
}

extern "C" void kernel_launch(void* const* d_in, const int* in_sizes, int n_in,
                              void* d_out, int out_size, void* d_ws, size_t ws_size,
                              hipStream_t stream) {
  const float* x = (const float*)d_in[0];
  const float* A_log = (const float*)d_in[1];
  const float* B = (const float*)d_in[2];
  const float* C = (const float*)d_in[3];
  const float* Dp = (const float*)d_in[4];
  const float* delta = (const float*)d_in[5];
  float* out = (float*)d_out;
  unsigned int* agg = (unsigned int*)d_ws;

  k_local<<<(NC * NP) / 256, 256, 0, stream>>>(x, A_log, delta, agg);
  k_scan<<<(P * 8) / 256, 256, 0, stream>>>(agg, A_log, delta);
  k_final<<<(NC * NP) / 256, 256, 0, stream>>>(x, A_log, B, C, Dp, delta, agg, out);
}

// Round 15
// 63.101 us; speedup vs baseline: 1.0579x; 1.0579x over previous
//
#include <hip/hip_runtime.h>

#define DM 2048
#define DS 16
#define SEQ 4096
#define P 4096      // batch * d_model independent scans
#define NP (P / 2)  // thread handles 2 adjacent channels
#define NC 64       // chunks (keeps 512 blocks with 2-channel threads)
#define LST 64      // SEQ / NC
#define UNR 16

// Rescaled state: g' = Abar*g + x  (Abar = exp(-delta*exp(A_log)));
// y = sum_n CB[n]*g[n] + D*x, CB = C*delta*B.  Params computed inline.
// 3 plain kernels (no cross-block sync / no coop launch / no NT hints —
// all measured slower on gfx950). Each thread owns TWO adjacent channels so
// every x load / y store is a float2 (512 B per wave-instr); NC=64 keeps the
// streaming grids at 512 blocks = 2 blocks/CU (R14 showed 1 block/CU -> 770
// GB/s; wave count dominates width).
// ws: agg [NC][P][16 bf16] (8 MB) — thread's 2 channels contiguous (64 B).

__device__ __forceinline__ unsigned short f2bf(float f) {
  unsigned int u = __builtin_bit_cast(unsigned int, f);
  u += 0x7fffu + ((u >> 16) & 1u);   // round-to-nearest-even
  return (unsigned short)(u >> 16);
}
__device__ __forceinline__ float bf2f(unsigned short s) {
  unsigned int u = ((unsigned int)s) << 16;
  return __builtin_bit_cast(float, u);
}

// ab for channels d, d+1 -> ab2[2][16]
__device__ __forceinline__ void load_ab2(const float* __restrict__ A_log, int d,
                                         float dl0, float dl1, float ab2[2][DS]) {
  const float4* alp = (const float4*)(A_log + d * DS);
#pragma unroll
  for (int c = 0; c < 2; c++) {
    float dl = c ? dl1 : dl0;
#pragma unroll
    for (int q = 0; q < 4; q++) {
      float4 v = alp[4 * c + q];
      ab2[c][4 * q + 0] = __expf(-dl * __expf(v.x));
      ab2[c][4 * q + 1] = __expf(-dl * __expf(v.y));
      ab2[c][4 * q + 2] = __expf(-dl * __expf(v.z));
      ab2[c][4 * q + 3] = __expf(-dl * __expf(v.w));
    }
  }
}

// Kernel 1: per-chunk local scan from g=0; store chunk-end aggregate (bf16).
__global__ __launch_bounds__(256, 2) void k_local(const float* __restrict__ x,
                                                  const float* __restrict__ A_log,
                                                  const float* __restrict__ delta,
                                                  unsigned int* __restrict__ agg) {
  int tid = blockIdx.x * 256 + threadIdx.x;   // NC * NP threads
  int p2 = tid & (NP - 1);
  int k = tid >> 11;            // NP = 2048
  int b = p2 >> 10;             // DM/2 = 1024 pairs per batch
  int d = (p2 & 1023) << 1;
  const float2* dlp = (const float2*)(delta + d);
  float2 dl = *dlp;
  float ab2[2][DS], g2[2][DS];
  load_ab2(A_log, d, dl.x, dl.y, ab2);
#pragma unroll
  for (int c = 0; c < 2; c++)
#pragma unroll
    for (int n = 0; n < DS; n++) g2[c][n] = 0.f;

  const float2* xp = (const float2*)(x + ((size_t)b * SEQ + (size_t)k * LST) * DM + d);
  const size_t str2 = DM / 2;   // float2 stride per time step
#pragma unroll 1
  for (int t = 0; t < LST; t += UNR) {
    float2 xv[UNR];
#pragma unroll
    for (int j = 0; j < UNR; j++) xv[j] = xp[(size_t)j * str2];
#pragma unroll
    for (int j = 0; j < UNR; j++) {
#pragma unroll
      for (int n = 0; n < DS; n++) g2[0][n] = fmaf(ab2[0][n], g2[0][n], xv[j].x);
#pragma unroll
      for (int n = 0; n < DS; n++) g2[1][n] = fmaf(ab2[1][n], g2[1][n], xv[j].y);
    }
    xp += (size_t)UNR * str2;
  }
  if (k < NC - 1) {  // last chunk's aggregate is never consumed
    unsigned int u[16];
#pragma unroll
    for (int c = 0; c < 2; c++)
#pragma unroll
      for (int q = 0; q < 8; q++)
        u[8 * c + q] = (unsigned int)f2bf(g2[c][2 * q]) |
                       ((unsigned int)f2bf(g2[c][2 * q + 1]) << 16);
    uint4* Ap = (uint4*)(agg + ((size_t)k * P + (size_t)b * DM + d) * 8);
    Ap[0] = make_uint4(u[0], u[1], u[2], u[3]);
    Ap[1] = make_uint4(u[4], u[5], u[6], u[7]);
    Ap[2] = make_uint4(u[8], u[9], u[10], u[11]);
    Ap[3] = make_uint4(u[12], u[13], u[14], u[15]);
  }
}

// Kernel 2: exclusive prefix scan over chunks; thread per (channel, n-pair).
__global__ __launch_bounds__(256) void k_scan(unsigned int* __restrict__ agg,
                                              const float* __restrict__ A_log,
                                              const float* __restrict__ delta) {
  int tid = blockIdx.x * 256 + threadIdx.x;  // P*8 threads
  int np = tid & 7;          // n-pair (n = 2*np, 2*np+1)
  int p = tid >> 3;
  int d = p & (DM - 1);
  float dl = delta[d];
  float pw0 = __expf(-dl * __expf(A_log[d * DS + 2 * np + 0]) * (float)LST);
  float pw1 = __expf(-dl * __expf(A_log[d * DS + 2 * np + 1]) * (float)LST);
  float c0 = 0.f, c1 = 0.f;
  unsigned int* Hp = agg + tid;
  const size_t stride = (size_t)P * 8;
#pragma unroll 1
  for (int k0 = 0; k0 < NC; k0 += 16) {
    unsigned int v[16];
#pragma unroll
    for (int j = 0; j < 16; j++) v[j] = Hp[(size_t)(k0 + j) * stride];
#pragma unroll
    for (int j = 0; j < 16; j++) {
      Hp[(size_t)(k0 + j) * stride] =
          (unsigned int)f2bf(c0) | ((unsigned int)f2bf(c1) << 16);
      c0 = fmaf(pw0, c0, bf2f((unsigned short)(v[j] & 0xffffu)));
      c1 = fmaf(pw1, c1, bf2f((unsigned short)(v[j] >> 16)));
    }
  }
}

// Kernel 3: rescan each chunk from its true start state; emit y (float2).
__global__ __launch_bounds__(256, 2) void k_final(const float* __restrict__ x,
                                                  const float* __restrict__ A_log,
                                                  const float* __restrict__ B,
                                                  const float* __restrict__ C,
                                                  const float* __restrict__ Dp,
                                                  const float* __restrict__ delta,
                                                  const unsigned int* __restrict__ agg,
                                                  float* __restrict__ out) {
  int tid = blockIdx.x * 256 + threadIdx.x;   // NC * NP threads
  int p2 = tid & (NP - 1);
  int k = tid >> 11;
  int b = p2 >> 10;
  int d = (p2 & 1023) << 1;
  const float2* dlp = (const float2*)(delta + d);
  float2 dl = *dlp;
  float ab2[2][DS], cb2[2][DS], g2[2][DS];
  load_ab2(A_log, d, dl.x, dl.y, ab2);
  {
    const float4* bp = (const float4*)(B + d * DS);
    const float4* cp = (const float4*)(C + d * DS);
#pragma unroll
    for (int c = 0; c < 2; c++) {
      float dlc = c ? dl.y : dl.x;
#pragma unroll
      for (int q = 0; q < 4; q++) {
        float4 bv = bp[4 * c + q];
        float4 cv = cp[4 * c + q];
        cb2[c][4 * q + 0] = cv.x * dlc * bv.x;
        cb2[c][4 * q + 1] = cv.y * dlc * bv.y;
        cb2[c][4 * q + 2] = cv.z * dlc * bv.z;
        cb2[c][4 * q + 3] = cv.w * dlc * bv.w;
      }
    }
  }
  {
    const uint4* Ap = (const uint4*)(agg + ((size_t)k * P + (size_t)b * DM + d) * 8);
#pragma unroll
    for (int c = 0; c < 2; c++) {
      uint4 u0 = Ap[2 * c], u1 = Ap[2 * c + 1];
      unsigned int u[8] = {u0.x, u0.y, u0.z, u0.w, u1.x, u1.y, u1.z, u1.w};
#pragma unroll
      for (int q = 0; q < 8; q++) {
        g2[c][2 * q + 0] = bf2f((unsigned short)(u[q] & 0xffffu));
        g2[c][2 * q + 1] = bf2f((unsigned short)(u[q] >> 16));
      }
    }
  }
  const float2* ddp = (const float2*)(Dp + d);
  float2 Dd = *ddp;
  size_t off = ((size_t)b * SEQ + (size_t)k * LST) * DM + d;
  const float2* xp = (const float2*)(x + off);
  float2* yp = (float2*)(out + off);
  const size_t str2 = DM / 2;
#pragma unroll 1
  for (int t = 0; t < LST; t += UNR) {
    float2 xv[UNR];
#pragma unroll
    for (int j = 0; j < UNR; j++) xv[j] = xp[(size_t)j * str2];
#pragma unroll
    for (int j = 0; j < UNR; j++) {
#pragma unroll
      for (int n = 0; n < DS; n++) g2[0][n] = fmaf(ab2[0][n], g2[0][n], xv[j].x);
#pragma unroll
      for (int n = 0; n < DS; n++) g2[1][n] = fmaf(ab2[1][n], g2[1][n], xv[j].y);
      float a0 = Dd.x * xv[j].x;
      float a1 = Dd.y * xv[j].y;
#pragma unroll
      for (int n = 0; n < DS; n++) a0 = fmaf(cb2[0][n], g2[0][n], a0);
#pragma unroll
      for (int n = 0; n < DS; n++) a1 = fmaf(cb2[1][n], g2[1][n], a1);
      yp[(size_t)j * str2] = make_float2(a0, a1);
    }
    xp += (size_t)UNR * str2;
    yp += (size_t)UNR * str2;
  }
}

extern "C" void kernel_launch(void* const* d_in, const int* in_sizes, int n_in,
                              void* d_out, int out_size, void* d_ws, size_t ws_size,
                              hipStream_t stream) {
  const float* x = (const float*)d_in[0];
  const float* A_log = (const float*)d_in[1];
  const float* B = (const float*)d_in[2];
  const float* C = (const float*)d_in[3];
  const float* Dp = (const float*)d_in[4];
  const float* delta = (const float*)d_in[5];
  float* out = (float*)d_out;
  unsigned int* agg = (unsigned int*)d_ws;

  k_local<<<(NC * NP) / 256, 256, 0, stream>>>(x, A_log, delta, agg);
  k_scan<<<(P * 8) / 256, 256, 0, stream>>>(agg, A_log, delta);
  k_final<<<(NC * NP) / 256, 256, 0, stream>>>(x, A_log, B, C, Dp, delta, agg, out);
}

// Round 16
// 49.751 us; speedup vs baseline: 1.3418x; 1.2683x over previous
//
#include <hip/hip_runtime.h>

#define DM 2048
#define DS 16
#define SEQ 4096
#define P 4096      // batch * d_model independent scans
#define NC 64       // chunks: NC*P = 262144 threads = 4096 waves = 16 waves/CU
#define LST 64      // SEQ / NC
#define UNR 16

// Rescaled state: g' = Abar*g + x  (Abar = exp(-delta*exp(A_log)));
// y = sum_n CB[n]*g[n] + D*x, CB = C*delta*B.  Params computed inline.
// 3 plain kernels; scalar 1-channel threads (float2/2-ch halves wave count —
// measured -40%: wave count is the BW lever on this pattern, not width).
// NC=64 doubles resident waves vs NC=32 (8 -> 16 waves/CU) at +16 MB agg.
// ws: agg [NC][P][16 bf16] (8 MB) — per-thread contiguous 32 B.

__device__ __forceinline__ unsigned short f2bf(float f) {
  unsigned int u = __builtin_bit_cast(unsigned int, f);
  u += 0x7fffu + ((u >> 16) & 1u);   // round-to-nearest-even
  return (unsigned short)(u >> 16);
}
__device__ __forceinline__ float bf2f(unsigned short s) {
  unsigned int u = ((unsigned int)s) << 16;
  return __builtin_bit_cast(float, u);
}

__device__ __forceinline__ void load_ab(const float* __restrict__ A_log, int d,
                                        float dl, float* ab) {
  const float4* alp = (const float4*)(A_log + d * DS);
#pragma unroll
  for (int q = 0; q < 4; q++) {
    float4 v = alp[q];
    ab[4 * q + 0] = __expf(-dl * __expf(v.x));
    ab[4 * q + 1] = __expf(-dl * __expf(v.y));
    ab[4 * q + 2] = __expf(-dl * __expf(v.z));
    ab[4 * q + 3] = __expf(-dl * __expf(v.w));
  }
}

// Kernel 1: per-chunk local scan from g=0; store chunk-end aggregate (bf16).
__global__ __launch_bounds__(256) void k_local(const float* __restrict__ x,
                                               const float* __restrict__ A_log,
                                               const float* __restrict__ delta,
                                               unsigned int* __restrict__ agg) {
  int tid = blockIdx.x * 256 + threadIdx.x;   // NC * P threads
  int p = tid & (P - 1);
  int k = tid >> 12;
  int b = p >> 11;
  int d = p & (DM - 1);
  float dl = delta[d];
  float ab[DS], g[DS];
  load_ab(A_log, d, dl, ab);
#pragma unroll
  for (int n = 0; n < DS; n++) g[n] = 0.f;

  const float* xp = x + ((size_t)b * SEQ + (size_t)k * LST) * DM + d;
#pragma unroll 1
  for (int t = 0; t < LST; t += UNR) {
    float xv[UNR];
#pragma unroll
    for (int j = 0; j < UNR; j++) xv[j] = xp[(size_t)j * DM];
#pragma unroll
    for (int j = 0; j < UNR; j++) {
#pragma unroll
      for (int n = 0; n < DS; n++) g[n] = fmaf(ab[n], g[n], xv[j]);
    }
    xp += (size_t)UNR * DM;
  }
  if (k < NC - 1) {  // last chunk's aggregate is never consumed
    unsigned int u[8];
#pragma unroll
    for (int q = 0; q < 8; q++)
      u[q] = (unsigned int)f2bf(g[2 * q]) | ((unsigned int)f2bf(g[2 * q + 1]) << 16);
    uint4* Ap = (uint4*)(agg + ((size_t)k * P + p) * 8);
    Ap[0] = make_uint4(u[0], u[1], u[2], u[3]);
    Ap[1] = make_uint4(u[4], u[5], u[6], u[7]);
  }
}

// Kernel 2: exclusive prefix scan over chunks; thread per (p, n-pair).
__global__ __launch_bounds__(256) void k_scan(unsigned int* __restrict__ agg,
                                              const float* __restrict__ A_log,
                                              const float* __restrict__ delta) {
  int tid = blockIdx.x * 256 + threadIdx.x;  // P*8 threads
  int np = tid & 7;          // n-pair (n = 2*np, 2*np+1)
  int p = tid >> 3;
  int d = p & (DM - 1);
  float dl = delta[d];
  float pw0 = __expf(-dl * __expf(A_log[d * DS + 2 * np + 0]) * (float)LST);
  float pw1 = __expf(-dl * __expf(A_log[d * DS + 2 * np + 1]) * (float)LST);
  float c0 = 0.f, c1 = 0.f;
  unsigned int* Hp = agg + tid;
  const size_t stride = (size_t)P * 8;
#pragma unroll 1
  for (int k0 = 0; k0 < NC; k0 += 16) {
    unsigned int v[16];
#pragma unroll
    for (int j = 0; j < 16; j++) v[j] = Hp[(size_t)(k0 + j) * stride];
#pragma unroll
    for (int j = 0; j < 16; j++) {
      Hp[(size_t)(k0 + j) * stride] =
          (unsigned int)f2bf(c0) | ((unsigned int)f2bf(c1) << 16);
      c0 = fmaf(pw0, c0, bf2f((unsigned short)(v[j] & 0xffffu)));
      c1 = fmaf(pw1, c1, bf2f((unsigned short)(v[j] >> 16)));
    }
  }
}

// Kernel 3: rescan each chunk from its true start state; emit y.
__global__ __launch_bounds__(256) void k_final(const float* __restrict__ x,
                                               const float* __restrict__ A_log,
                                               const float* __restrict__ B,
                                               const float* __restrict__ C,
                                               const float* __restrict__ Dp,
                                               const float* __restrict__ delta,
                                               const unsigned int* __restrict__ agg,
                                               float* __restrict__ out) {
  int tid = blockIdx.x * 256 + threadIdx.x;   // NC * P threads
  int p = tid & (P - 1);
  int k = tid >> 12;
  int b = p >> 11;
  int d = p & (DM - 1);
  float dl = delta[d];
  float ab[DS], cb[DS], g[DS];
  load_ab(A_log, d, dl, ab);
  {
    const float4* bp = (const float4*)(B + d * DS);
    const float4* cp = (const float4*)(C + d * DS);
#pragma unroll
    for (int q = 0; q < 4; q++) {
      float4 bv = bp[q];
      float4 cv = cp[q];
      cb[4 * q + 0] = cv.x * dl * bv.x;
      cb[4 * q + 1] = cv.y * dl * bv.y;
      cb[4 * q + 2] = cv.z * dl * bv.z;
      cb[4 * q + 3] = cv.w * dl * bv.w;
    }
  }
  {
    const uint4* Ap = (const uint4*)(agg + ((size_t)k * P + p) * 8);
    uint4 u0 = Ap[0], u1 = Ap[1];
    unsigned int u[8] = {u0.x, u0.y, u0.z, u0.w, u1.x, u1.y, u1.z, u1.w};
#pragma unroll
    for (int q = 0; q < 8; q++) {
      g[2 * q + 0] = bf2f((unsigned short)(u[q] & 0xffffu));
      g[2 * q + 1] = bf2f((unsigned short)(u[q] >> 16));
    }
  }
  float Dd = Dp[d];
  size_t off = ((size_t)b * SEQ + (size_t)k * LST) * DM + d;
  const float* xp = x + off;
  float* yp = out + off;
#pragma unroll 1
  for (int t = 0; t < LST; t += UNR) {
    float xv[UNR];
#pragma unroll
    for (int j = 0; j < UNR; j++) xv[j] = xp[(size_t)j * DM];
#pragma unroll
    for (int j = 0; j < UNR; j++) {
#pragma unroll
      for (int n = 0; n < DS; n++) g[n] = fmaf(ab[n], g[n], xv[j]);
      // tree-structured dot: cuts the serial FMA chain 16 -> 4 levels
      float s[8];
#pragma unroll
      for (int q = 0; q < 8; q++)
        s[q] = fmaf(cb[2 * q], g[2 * q], cb[2 * q + 1] * g[2 * q + 1]);
      float t0 = (s[0] + s[1]) + (s[2] + s[3]);
      float t1 = (s[4] + s[5]) + (s[6] + s[7]);
      yp[(size_t)j * DM] = fmaf(Dd, xv[j], t0 + t1);
    }
    xp += (size_t)UNR * DM;
    yp += (size_t)UNR * DM;
  }
}

extern "C" void kernel_launch(void* const* d_in, const int* in_sizes, int n_in,
                              void* d_out, int out_size, void* d_ws, size_t ws_size,
                              hipStream_t stream) {
  const float* x = (const float*)d_in[0];
  const float* A_log = (const float*)d_in[1];
  const float* B = (const float*)d_in[2];
  const float* C = (const float*)d_in[3];
  const float* Dp = (const float*)d_in[4];
  const float* delta = (const float*)d_in[5];
  float* out = (float*)d_out;
  unsigned int* agg = (unsigned int*)d_ws;

  k_local<<<(NC * P) / 256, 256, 0, stream>>>(x, A_log, delta, agg);
  k_scan<<<(P * 8) / 256, 256, 0, stream>>>(agg, A_log, delta);
  k_final<<<(NC * P) / 256, 256, 0, stream>>>(x, A_log, B, C, Dp, delta, agg, out);
}

// Round 17
// 46.868 us; speedup vs baseline: 1.4244x; 1.0615x over previous
//
#include <hip/hip_runtime.h>

#define DM 2048
#define DS 16
#define SEQ 4096
#define P 4096      // batch * d_model independent scans
#define NC 32       // chunks
#define LST 128     // SEQ / NC
#define UNR 16

// BEST CONFIG (R13, 47.07 us). Rescaled state: g' = Abar*g + x
// (Abar = exp(-delta*exp(A_log)));  y = sum_n CB[n]*g[n] + D*x, CB = C*delta*B.
// 3 plain kernels. Measured-and-rejected on gfx950: coop grid-sync fusion,
// decoupled-lookback flag fusion (device-scope acquires poison streaming),
// NT load/store hints, float2 2-channel threads (halves waves), NC=64
// (agg traffic outweighs), LDS staging (barrier-bound), register-resident x
// (VGPR spill). Wave count >= 8/CU suffices; pattern rate ~5 TB/s is the
// intrinsic ceiling for 4 B/lane strided streams.
// ws: agg [NC][P][16 bf16] (4 MB) — per-thread contiguous 32 B.

__device__ __forceinline__ unsigned short f2bf(float f) {
  unsigned int u = __builtin_bit_cast(unsigned int, f);
  u += 0x7fffu + ((u >> 16) & 1u);   // round-to-nearest-even
  return (unsigned short)(u >> 16);
}
__device__ __forceinline__ float bf2f(unsigned short s) {
  unsigned int u = ((unsigned int)s) << 16;
  return __builtin_bit_cast(float, u);
}

__device__ __forceinline__ void load_ab(const float* __restrict__ A_log, int d,
                                        float dl, float* ab) {
  const float4* alp = (const float4*)(A_log + d * DS);
#pragma unroll
  for (int q = 0; q < 4; q++) {
    float4 v = alp[q];
    ab[4 * q + 0] = __expf(-dl * __expf(v.x));
    ab[4 * q + 1] = __expf(-dl * __expf(v.y));
    ab[4 * q + 2] = __expf(-dl * __expf(v.z));
    ab[4 * q + 3] = __expf(-dl * __expf(v.w));
  }
}

// Kernel 1: per-chunk local scan from g=0; store chunk-end aggregate (bf16).
__global__ __launch_bounds__(256) void k_local(const float* __restrict__ x,
                                               const float* __restrict__ A_log,
                                               const float* __restrict__ delta,
                                               unsigned int* __restrict__ agg) {
  int tid = blockIdx.x * 256 + threadIdx.x;
  int p = tid & (P - 1);
  int k = tid >> 12;
  int b = p >> 11;
  int d = p & (DM - 1);
  float dl = delta[d];
  float ab[DS], g[DS];
  load_ab(A_log, d, dl, ab);
#pragma unroll
  for (int n = 0; n < DS; n++) g[n] = 0.f;

  const float* xp = x + ((size_t)b * SEQ + (size_t)k * LST) * DM + d;
#pragma unroll 1
  for (int t = 0; t < LST; t += UNR) {
    float xv[UNR];
#pragma unroll
    for (int j = 0; j < UNR; j++) xv[j] = xp[(size_t)j * DM];
#pragma unroll
    for (int j = 0; j < UNR; j++) {
#pragma unroll
      for (int n = 0; n < DS; n++) g[n] = fmaf(ab[n], g[n], xv[j]);
    }
    xp += (size_t)UNR * DM;
  }
  if (k < NC - 1) {  // last chunk's aggregate is never consumed
    unsigned int u[8];
#pragma unroll
    for (int q = 0; q < 8; q++)
      u[q] = (unsigned int)f2bf(g[2 * q]) | ((unsigned int)f2bf(g[2 * q + 1]) << 16);
    uint4* Ap = (uint4*)(agg + ((size_t)k * P + p) * 8);
    Ap[0] = make_uint4(u[0], u[1], u[2], u[3]);
    Ap[1] = make_uint4(u[4], u[5], u[6], u[7]);
  }
}

// Kernel 2: exclusive prefix scan over chunks; thread per (p, n-pair).
// Reads packed bf16 pairs, scans in fp32, writes bf16 exclusive prefixes.
__global__ __launch_bounds__(256) void k_scan(unsigned int* __restrict__ agg,
                                              const float* __restrict__ A_log,
                                              const float* __restrict__ delta) {
  int tid = blockIdx.x * 256 + threadIdx.x;  // P*8 threads
  int np = tid & 7;          // n-pair index (n = 2*np, 2*np+1)
  int p = tid >> 3;
  int d = p & (DM - 1);
  float dl = delta[d];
  float pw0 = __expf(-dl * __expf(A_log[d * DS + 2 * np + 0]) * (float)LST);
  float pw1 = __expf(-dl * __expf(A_log[d * DS + 2 * np + 1]) * (float)LST);
  float c0 = 0.f, c1 = 0.f;
  unsigned int* Hp = agg + tid;
  const size_t stride = (size_t)P * 8;
  unsigned int v[NC];
#pragma unroll
  for (int j = 0; j < NC; j++) v[j] = Hp[(size_t)j * stride];
#pragma unroll
  for (int j = 0; j < NC; j++) {
    Hp[(size_t)j * stride] =
        (unsigned int)f2bf(c0) | ((unsigned int)f2bf(c1) << 16);
    c0 = fmaf(pw0, c0, bf2f((unsigned short)(v[j] & 0xffffu)));
    c1 = fmaf(pw1, c1, bf2f((unsigned short)(v[j] >> 16)));
  }
}

// Kernel 3: rescan each chunk from its true start state; emit y.
__global__ __launch_bounds__(256) void k_final(const float* __restrict__ x,
                                               const float* __restrict__ A_log,
                                               const float* __restrict__ B,
                                               const float* __restrict__ C,
                                               const float* __restrict__ Dp,
                                               const float* __restrict__ delta,
                                               const unsigned int* __restrict__ agg,
                                               float* __restrict__ out) {
  int tid = blockIdx.x * 256 + threadIdx.x;
  int p = tid & (P - 1);
  int k = tid >> 12;
  int b = p >> 11;
  int d = p & (DM - 1);
  float dl = delta[d];
  float ab[DS], cb[DS], g[DS];
  load_ab(A_log, d, dl, ab);
  {
    const float4* bp = (const float4*)(B + d * DS);
    const float4* cp = (const float4*)(C + d * DS);
#pragma unroll
    for (int q = 0; q < 4; q++) {
      float4 bv = bp[q];
      float4 cv = cp[q];
      cb[4 * q + 0] = cv.x * dl * bv.x;
      cb[4 * q + 1] = cv.y * dl * bv.y;
      cb[4 * q + 2] = cv.z * dl * bv.z;
      cb[4 * q + 3] = cv.w * dl * bv.w;
    }
  }
  {
    const uint4* Ap = (const uint4*)(agg + ((size_t)k * P + p) * 8);
    uint4 u0 = Ap[0], u1 = Ap[1];
    unsigned int u[8] = {u0.x, u0.y, u0.z, u0.w, u1.x, u1.y, u1.z, u1.w};
#pragma unroll
    for (int q = 0; q < 8; q++) {
      g[2 * q + 0] = bf2f((unsigned short)(u[q] & 0xffffu));
      g[2 * q + 1] = bf2f((unsigned short)(u[q] >> 16));
    }
  }
  float Dd = Dp[d];
  size_t off = ((size_t)b * SEQ + (size_t)k * LST) * DM + d;
  const float* xp = x + off;
  float* yp = out + off;
#pragma unroll 1
  for (int t = 0; t < LST; t += UNR) {
    float xv[UNR];
#pragma unroll
    for (int j = 0; j < UNR; j++) xv[j] = xp[(size_t)j * DM];
#pragma unroll
    for (int j = 0; j < UNR; j++) {
#pragma unroll
      for (int n = 0; n < DS; n++) g[n] = fmaf(ab[n], g[n], xv[j]);
      float acc = Dd * xv[j];
#pragma unroll
      for (int n = 0; n < DS; n++) acc = fmaf(cb[n], g[n], acc);
      yp[(size_t)j * DM] = acc;
    }
    xp += (size_t)UNR * DM;
    yp += (size_t)UNR * DM;
  }
}

extern "C" void kernel_launch(void* const* d_in, const int* in_sizes, int n_in,
                              void* d_out, int out_size, void* d_ws, size_t ws_size,
                              hipStream_t stream) {
  const float* x = (const float*)d_in[0];
  const float* A_log = (const float*)d_in[1];
  const float* B = (const float*)d_in[2];
  const float* C = (const float*)d_in[3];
  const float* Dp = (const float*)d_in[4];
  const float* delta = (const float*)d_in[5];
  float* out = (float*)d_out;
  unsigned int* agg = (unsigned int*)d_ws;

  k_local<<<(NC * P) / 256, 256, 0, stream>>>(x, A_log, delta, agg);
  k_scan<<<(P * 8) / 256, 256, 0, stream>>>(agg, A_log, delta);
  k_final<<<(NC * P) / 256, 256, 0, stream>>>(x, A_log, B, C, Dp, delta, agg, out);
}

// Round 18
// 46.214 us; speedup vs baseline: 1.4445x; 1.0142x over previous
//
#include <hip/hip_runtime.h>

#define DM 2048
#define DS 16
#define SEQ 4096
#define P 4096      // batch * d_model independent scans
#define NC 32       // chunks
#define LST 128     // SEQ / NC
#define UNR 16

// R13 structure (best, 46.9-47.1 us) + ONE change: y stores are nontemporal
// (no-allocate) so the 64 MB y stream does not evict x from L2/L3 before
// k_final's re-read. Isolated A/B vs R17.
// Measured-and-rejected on gfx950: coop grid-sync fusion, decoupled-lookback
// flag fusion, NT on loads+stores jointly, float2 2-ch threads, NC=64,
// LDS staging, register-resident x, UNR 8/32, 2-kernel lookback.
// ws: agg [NC][P][16 bf16] (4 MB) — per-thread contiguous 32 B.

__device__ __forceinline__ unsigned short f2bf(float f) {
  unsigned int u = __builtin_bit_cast(unsigned int, f);
  u += 0x7fffu + ((u >> 16) & 1u);   // round-to-nearest-even
  return (unsigned short)(u >> 16);
}
__device__ __forceinline__ float bf2f(unsigned short s) {
  unsigned int u = ((unsigned int)s) << 16;
  return __builtin_bit_cast(float, u);
}

__device__ __forceinline__ void load_ab(const float* __restrict__ A_log, int d,
                                        float dl, float* ab) {
  const float4* alp = (const float4*)(A_log + d * DS);
#pragma unroll
  for (int q = 0; q < 4; q++) {
    float4 v = alp[q];
    ab[4 * q + 0] = __expf(-dl * __expf(v.x));
    ab[4 * q + 1] = __expf(-dl * __expf(v.y));
    ab[4 * q + 2] = __expf(-dl * __expf(v.z));
    ab[4 * q + 3] = __expf(-dl * __expf(v.w));
  }
}

// Kernel 1: per-chunk local scan from g=0; store chunk-end aggregate (bf16).
__global__ __launch_bounds__(256) void k_local(const float* __restrict__ x,
                                               const float* __restrict__ A_log,
                                               const float* __restrict__ delta,
                                               unsigned int* __restrict__ agg) {
  int tid = blockIdx.x * 256 + threadIdx.x;
  int p = tid & (P - 1);
  int k = tid >> 12;
  int b = p >> 11;
  int d = p & (DM - 1);
  float dl = delta[d];
  float ab[DS], g[DS];
  load_ab(A_log, d, dl, ab);
#pragma unroll
  for (int n = 0; n < DS; n++) g[n] = 0.f;

  const float* xp = x + ((size_t)b * SEQ + (size_t)k * LST) * DM + d;
#pragma unroll 1
  for (int t = 0; t < LST; t += UNR) {
    float xv[UNR];
#pragma unroll
    for (int j = 0; j < UNR; j++) xv[j] = xp[(size_t)j * DM];
#pragma unroll
    for (int j = 0; j < UNR; j++) {
#pragma unroll
      for (int n = 0; n < DS; n++) g[n] = fmaf(ab[n], g[n], xv[j]);
    }
    xp += (size_t)UNR * DM;
  }
  if (k < NC - 1) {  // last chunk's aggregate is never consumed
    unsigned int u[8];
#pragma unroll
    for (int q = 0; q < 8; q++)
      u[q] = (unsigned int)f2bf(g[2 * q]) | ((unsigned int)f2bf(g[2 * q + 1]) << 16);
    uint4* Ap = (uint4*)(agg + ((size_t)k * P + p) * 8);
    Ap[0] = make_uint4(u[0], u[1], u[2], u[3]);
    Ap[1] = make_uint4(u[4], u[5], u[6], u[7]);
  }
}

// Kernel 2: exclusive prefix scan over chunks; thread per (p, n-pair).
__global__ __launch_bounds__(256) void k_scan(unsigned int* __restrict__ agg,
                                              const float* __restrict__ A_log,
                                              const float* __restrict__ delta) {
  int tid = blockIdx.x * 256 + threadIdx.x;  // P*8 threads
  int np = tid & 7;          // n-pair index (n = 2*np, 2*np+1)
  int p = tid >> 3;
  int d = p & (DM - 1);
  float dl = delta[d];
  float pw0 = __expf(-dl * __expf(A_log[d * DS + 2 * np + 0]) * (float)LST);
  float pw1 = __expf(-dl * __expf(A_log[d * DS + 2 * np + 1]) * (float)LST);
  float c0 = 0.f, c1 = 0.f;
  unsigned int* Hp = agg + tid;
  const size_t stride = (size_t)P * 8;
  unsigned int v[NC];
#pragma unroll
  for (int j = 0; j < NC; j++) v[j] = Hp[(size_t)j * stride];
#pragma unroll
  for (int j = 0; j < NC; j++) {
    Hp[(size_t)j * stride] =
        (unsigned int)f2bf(c0) | ((unsigned int)f2bf(c1) << 16);
    c0 = fmaf(pw0, c0, bf2f((unsigned short)(v[j] & 0xffffu)));
    c1 = fmaf(pw1, c1, bf2f((unsigned short)(v[j] >> 16)));
  }
}

// Kernel 3: rescan each chunk from its true start state; emit y (NT stores).
__global__ __launch_bounds__(256) void k_final(const float* __restrict__ x,
                                               const float* __restrict__ A_log,
                                               const float* __restrict__ B,
                                               const float* __restrict__ C,
                                               const float* __restrict__ Dp,
                                               const float* __restrict__ delta,
                                               const unsigned int* __restrict__ agg,
                                               float* __restrict__ out) {
  int tid = blockIdx.x * 256 + threadIdx.x;
  int p = tid & (P - 1);
  int k = tid >> 12;
  int b = p >> 11;
  int d = p & (DM - 1);
  float dl = delta[d];
  float ab[DS], cb[DS], g[DS];
  load_ab(A_log, d, dl, ab);
  {
    const float4* bp = (const float4*)(B + d * DS);
    const float4* cp = (const float4*)(C + d * DS);
#pragma unroll
    for (int q = 0; q < 4; q++) {
      float4 bv = bp[q];
      float4 cv = cp[q];
      cb[4 * q + 0] = cv.x * dl * bv.x;
      cb[4 * q + 1] = cv.y * dl * bv.y;
      cb[4 * q + 2] = cv.z * dl * bv.z;
      cb[4 * q + 3] = cv.w * dl * bv.w;
    }
  }
  {
    const uint4* Ap = (const uint4*)(agg + ((size_t)k * P + p) * 8);
    uint4 u0 = Ap[0], u1 = Ap[1];
    unsigned int u[8] = {u0.x, u0.y, u0.z, u0.w, u1.x, u1.y, u1.z, u1.w};
#pragma unroll
    for (int q = 0; q < 8; q++) {
      g[2 * q + 0] = bf2f((unsigned short)(u[q] & 0xffffu));
      g[2 * q + 1] = bf2f((unsigned short)(u[q] >> 16));
    }
  }
  float Dd = Dp[d];
  size_t off = ((size_t)b * SEQ + (size_t)k * LST) * DM + d;
  const float* xp = x + off;
  float* yp = out + off;
#pragma unroll 1
  for (int t = 0; t < LST; t += UNR) {
    float xv[UNR];
#pragma unroll
    for (int j = 0; j < UNR; j++) xv[j] = xp[(size_t)j * DM];
#pragma unroll
    for (int j = 0; j < UNR; j++) {
#pragma unroll
      for (int n = 0; n < DS; n++) g[n] = fmaf(ab[n], g[n], xv[j]);
      float acc = Dd * xv[j];
#pragma unroll
      for (int n = 0; n < DS; n++) acc = fmaf(cb[n], g[n], acc);
      __builtin_nontemporal_store(acc, yp + (size_t)j * DM);
    }
    xp += (size_t)UNR * DM;
    yp += (size_t)UNR * DM;
  }
}

extern "C" void kernel_launch(void* const* d_in, const int* in_sizes, int n_in,
                              void* d_out, int out_size, void* d_ws, size_t ws_size,
                              hipStream_t stream) {
  const float* x = (const float*)d_in[0];
  const float* A_log = (const float*)d_in[1];
  const float* B = (const float*)d_in[2];
  const float* C = (const float*)d_in[3];
  const float* Dp = (const float*)d_in[4];
  const float* delta = (const float*)d_in[5];
  float* out = (float*)d_out;
  unsigned int* agg = (unsigned int*)d_ws;

  k_local<<<(NC * P) / 256, 256, 0, stream>>>(x, A_log, delta, agg);
  k_scan<<<(P * 8) / 256, 256, 0, stream>>>(agg, A_log, delta);
  k_final<<<(NC * P) / 256, 256, 0, stream>>>(x, A_log, B, C, Dp, delta, agg, out);
}